// Round 1
// baseline (261.357 us; speedup 1.0000x reference)
//
#include <hip/hip_runtime.h>
#include <hip/hip_bf16.h>

#define T_TOKENS 2048
#define D_EMBD 768
#define N_EXP 64
#define EW 256
#define TOPK 8
#define TW (N_EXP*EW)
#define PAD_SLOTS 18432   // 16384 + 64*31 rounded up
#define OUT_BASE (2048*768)

typedef __attribute__((ext_vector_type(8))) short bf16x8;
typedef __attribute__((ext_vector_type(4))) float f32x4;

typedef __attribute__((address_space(1))) void GAS;
typedef __attribute__((address_space(3))) void LAS;
#define GLOAD16(g, l) __builtin_amdgcn_global_load_lds((GAS*)(g), (LAS*)(l), 16, 0, 0)

// ---------------- init ----------------
__global__ void k_init(int* counts, int* cursor, float* psum, float* scal, float* wgt_slot) {
  int i = blockIdx.x*256 + threadIdx.x;
  if (i < N_EXP) { counts[i] = 0; cursor[i] = 0; psum[i] = 0.f; }
  if (i < 2) scal[i] = 0.f;
  if (i < PAD_SLOTS) wgt_slot[i] = 0.f;
}

// ---------------- x -> bf16 ----------------
__global__ void k_cvt_x(const float* __restrict__ x, __hip_bfloat16* __restrict__ xb) {
  int i = blockIdx.x*256 + threadIdx.x;   // 393216 threads, 4 elems each
  float4 v = reinterpret_cast<const float4*>(x)[i];
  union { __hip_bfloat16 b; unsigned short u; } c0, c1, c2, c3;
  c0.b = __float2bfloat16(v.x); c1.b = __float2bfloat16(v.y);
  c2.b = __float2bfloat16(v.z); c3.b = __float2bfloat16(v.w);
  ushort4 o; o.x = c0.u; o.y = c1.u; o.z = c2.u; o.w = c3.u;
  reinterpret_cast<ushort4*>(xb)[i] = o;
}

// ---------------- transpose + convert: src[R][C] f32 -> dst[C][R] bf16 ----------------
__global__ void k_transpose_cvt(const float* __restrict__ src, __hip_bfloat16* __restrict__ dst,
                                int R, int C) {
  __shared__ float tile[32][33];
  int bx = blockIdx.x*32, by = blockIdx.y*32;
  int tx = threadIdx.x & 31, ty = threadIdx.x >> 5;   // 32 x 8
  #pragma unroll
  for (int i = 0; i < 32; i += 8)
    tile[ty+i][tx] = src[(size_t)(by+ty+i)*C + bx+tx];
  __syncthreads();
  #pragma unroll
  for (int i = 0; i < 32; i += 8)
    dst[(size_t)(bx+ty+i)*R + by+tx] = __float2bfloat16(tile[tx][ty+i]);
}

// ---------------- router: logits, sigmoid, top-8, losses ----------------
__global__ void k_router(const float* __restrict__ x, const float* __restrict__ rw,
                         int* __restrict__ sel_e, float* __restrict__ sel_w,
                         int* __restrict__ counts, float* __restrict__ psum,
                         float* __restrict__ scal) {
  __shared__ float xs[4*D_EMBD];
  int t0 = blockIdx.x*4;
  int tid = threadIdx.x;
  const float4* xsrc = reinterpret_cast<const float4*>(x + (size_t)t0*D_EMBD);
  float4* xd = reinterpret_cast<float4*>(xs);
  for (int i = tid; i < D_EMBD; i += 256) xd[i] = xsrc[i];
  __syncthreads();
  int wv = tid >> 6, lane = tid & 63;
  int t = t0 + wv;
  const float4* r4 = reinterpret_cast<const float4*>(rw + (size_t)lane*D_EMBD);
  const float4* x4 = reinterpret_cast<const float4*>(xs + wv*D_EMBD);
  float acc = 0.f;
  #pragma unroll 4
  for (int i = 0; i < D_EMBD/4; i++) {
    float4 a = x4[i], b = r4[i];
    acc += a.x*b.x + a.y*b.y + a.z*b.z + a.w*b.w;
  }
  float logit = acc;
  float prob = 1.f/(1.f + expf(-logit));
  // logsumexp (fp32, stable)
  float mx = logit;
  for (int s = 32; s; s >>= 1) mx = fmaxf(mx, __shfl_xor(mx, s, 64));
  float ex = expf(logit - mx);
  float sse = ex;
  for (int s = 32; s; s >>= 1) sse += __shfl_xor(sse, s, 64);
  float lse = mx + logf(sse);
  float ps = prob;
  for (int s = 32; s; s >>= 1) ps += __shfl_xor(ps, s, 64);
  if (lane == 0) { atomicAdd(&scal[0], lse*lse); atomicAdd(&scal[1], ps); }
  atomicAdd(&psum[lane], prob);
  // top-8 with jax tie-break (lower index wins on equality)
  float cur = prob;
  float selp = 0.f; int sele = 0;
  #pragma unroll
  for (int k = 0; k < TOPK; k++) {
    float bp = cur; int be = lane;
    for (int s = 32; s; s >>= 1) {
      float op = __shfl_xor(bp, s, 64);
      int oe = __shfl_xor(be, s, 64);
      if (op > bp || (op == bp && oe < be)) { bp = op; be = oe; }
    }
    if (lane == be) cur = -1.f;
    if (lane == k) { selp = bp; sele = be; }
  }
  float wsum = (lane < TOPK) ? selp : 0.f;
  for (int s = 32; s; s >>= 1) wsum += __shfl_xor(wsum, s, 64);
  if (lane < TOPK) {
    sel_e[t*TOPK + lane] = sele;
    sel_w[t*TOPK + lane] = selp / (wsum + 1e-20f);
    atomicAdd(&counts[sele], 1);
  }
}

// ---------------- schedule: padded offsets + tile list (trivial serial) ----------------
__global__ void k_schedule(const int* __restrict__ counts, int* __restrict__ offsets,
                           int* __restrict__ sched_e, int* __restrict__ sched_r0,
                           int* __restrict__ ntiles) {
  if (threadIdx.x == 0) {
    int off = 0, tt = 0;
    for (int e = 0; e < N_EXP; e++) {
      offsets[e] = off;
      int tiles = (counts[e] + 31) >> 5;
      for (int i = 0; i < tiles; i++) { sched_e[tt] = e; sched_r0[tt] = off + i*32; tt++; }
      off += tiles << 5;
    }
    ntiles[0] = tt;
  }
}

// ---------------- assign tokens to slots ----------------
__global__ void k_assign(const int* __restrict__ sel_e, const float* __restrict__ sel_w,
                         const int* __restrict__ offsets, int* __restrict__ cursor,
                         int* __restrict__ tok_slot, float* __restrict__ wgt_slot,
                         int* __restrict__ slot_tk) {
  int i = blockIdx.x*256 + threadIdx.x;   // 16384
  int e = sel_e[i];
  int pos = atomicAdd(&cursor[e], 1);
  int slot = offsets[e] + pos;
  tok_slot[slot] = i >> 3;
  wgt_slot[slot] = sel_w[i];
  slot_tk[i] = slot;
}

// ---------------- grouped GEMM (MODE 1: x@W1 -> relu^2*gate -> h ; MODE 2: h@W2 -> y) ----------------
// tile: 32 rows x 256 cols, BK=64, 4 waves, mfma 16x16x32 bf16.
// LDS chunk swizzle: chunk kc at (row) stores global chunk (kc ^ (row&7)); same XOR on read.
template<int MODE>
__global__ __launch_bounds__(256) void k_moe_gemm(
    const __hip_bfloat16* __restrict__ Ab, const __hip_bfloat16* __restrict__ Bt,
    const int* __restrict__ sched_e, const int* __restrict__ sched_r0,
    const int* __restrict__ ntiles, const int* __restrict__ tok_slot,
    const float* __restrict__ wgt_slot, void* __restrict__ outp) {
  int tile = blockIdx.x;
  if (tile >= ntiles[0]) return;
  int e = sched_e[tile], r0 = sched_r0[tile];
  int nch = (MODE == 2) ? blockIdx.y : 0;
  constexpr int KT = (MODE == 1) ? 768 : 256;
  __shared__ __hip_bfloat16 As[32*64];
  __shared__ __hip_bfloat16 Bs[256*64];
  int tid = threadIdx.x;
  int arow = tid >> 3, akc = tid & 7;
  size_t a_base;
  if (MODE == 1) {
    int tok = tok_slot[r0 + arow];
    tok = min(max(tok, 0), T_TOKENS - 1);   // padded slots clamp; gate=0 kills them
    a_base = (size_t)tok * D_EMBD;
  } else {
    a_base = (size_t)(r0 + arow) * EW;
  }
  int a_off = ((akc ^ (arow & 7)) << 3);
  size_t b_base; int b_str;
  if (MODE == 1) { b_str = D_EMBD; b_base = (size_t)(e*EW) * D_EMBD; }
  else { b_str = TW; b_base = (size_t)(nch*EW) * TW + (size_t)e*EW; }

  f32x4 acc[2][4];
  f32x4 z = {0.f, 0.f, 0.f, 0.f};
  #pragma unroll
  for (int m = 0; m < 2; m++)
    #pragma unroll
    for (int n = 0; n < 4; n++) acc[m][n] = z;

  int wv = tid >> 6, lane = tid & 63;
  int l15 = lane & 15, l4 = lane >> 4;
  int brow_ = tid >> 3, bkc = tid & 7;

  for (int k0 = 0; k0 < KT; k0 += 64) {
    __syncthreads();
    GLOAD16(Ab + a_base + k0 + a_off, As + tid*8);
    #pragma unroll
    for (int i = 0; i < 8; i++) {
      int br = i*32 + brow_;
      int boff = ((bkc ^ (br & 7)) << 3);
      GLOAD16(Bt + b_base + (size_t)br*b_str + k0 + boff, Bs + (i*256 + tid)*8);
    }
    asm volatile("s_waitcnt vmcnt(0)" ::: "memory");
    __syncthreads();
    const bf16x8* A8 = reinterpret_cast<const bf16x8*>(As);
    const bf16x8* B8 = reinterpret_cast<const bf16x8*>(Bs);
    bf16x8 af[2][2], bq[4][2];
    #pragma unroll
    for (int m = 0; m < 2; m++) {
      int ra = m*16 + l15;
      #pragma unroll
      for (int kk = 0; kk < 2; kk++)
        af[m][kk] = A8[ra*8 + ((kk*4 + l4) ^ (ra & 7))];
    }
    #pragma unroll
    for (int n = 0; n < 4; n++) {
      int rb = wv*64 + n*16 + l15;
      #pragma unroll
      for (int kk = 0; kk < 2; kk++)
        bq[n][kk] = B8[rb*8 + ((kk*4 + l4) ^ (rb & 7))];
    }
    #pragma unroll
    for (int kk = 0; kk < 2; kk++)
      #pragma unroll
      for (int m = 0; m < 2; m++)
        #pragma unroll
        for (int n = 0; n < 4; n++)
          acc[m][n] = __builtin_amdgcn_mfma_f32_16x16x32_bf16(af[m][kk], bq[n][kk], acc[m][n], 0, 0, 0);
  }

  if (MODE == 1) {
    __hip_bfloat16* h = (__hip_bfloat16*)outp;
    #pragma unroll
    for (int m = 0; m < 2; m++)
      #pragma unroll
      for (int j = 0; j < 4; j++) {
        int r = r0 + m*16 + l4*4 + j;
        float wg = wgt_slot[r];
        #pragma unroll
        for (int n = 0; n < 4; n++) {
          int col = wv*64 + n*16 + l15;
          float v = fmaxf(acc[m][n][j], 0.f);
          h[(size_t)r*EW + col] = __float2bfloat16(v*v*wg);
        }
      }
  } else {
    __hip_bfloat16* y = (__hip_bfloat16*)outp;
    #pragma unroll
    for (int m = 0; m < 2; m++)
      #pragma unroll
      for (int j = 0; j < 4; j++) {
        int r = r0 + m*16 + l4*4 + j;
        #pragma unroll
        for (int n = 0; n < 4; n++) {
          int col = nch*EW + wv*64 + n*16 + l15;
          y[(size_t)r*D_EMBD + col] = __float2bfloat16(acc[m][n][j]);
        }
      }
  }
}

// ---------------- combine 8 expert rows per token ----------------
__global__ void k_combine(const __hip_bfloat16* __restrict__ y, const int* __restrict__ slot_tk,
                          float* __restrict__ out) {
  __shared__ int s[TOPK];
  int t = blockIdx.x, tid = threadIdx.x;
  if (tid < TOPK) s[tid] = slot_tk[t*TOPK + tid];
  __syncthreads();
  for (int c = tid; c < D_EMBD; c += 256) {
    float a = 0.f;
    #pragma unroll
    for (int k = 0; k < TOPK; k++)
      a += __bfloat162float(y[(size_t)s[k]*D_EMBD + c]);
    out[(size_t)t*D_EMBD + c] = a;
  }
}

// ---------------- aux losses + f_i ----------------
__global__ void k_finalize(const int* __restrict__ counts, const float* __restrict__ psum,
                           const float* __restrict__ scal, float* __restrict__ out) {
  __shared__ float part[N_EXP];
  int e = threadIdx.x;
  float f = (float)counts[e] / 16384.f;
  float p = psum[e] / 2048.f;
  part[e] = f * p;
  out[OUT_BASE + 3 + e] = f;
  __syncthreads();
  if (e == 0) {
    float s = 0.f;
    for (int i = 0; i < N_EXP; i++) s += part[i];
    out[OUT_BASE + 0] = scal[0] / 2048.f;      // router_z_loss
    out[OUT_BASE + 1] = 64.f * s;              // load_balance_loss
    out[OUT_BASE + 2] = scal[1] / 2048.f;      // compute_loss
  }
}

extern "C" void kernel_launch(void* const* d_in, const int* in_sizes, int n_in,
                              void* d_out, int out_size, void* d_ws, size_t ws_size,
                              hipStream_t stream) {
  const float* x  = (const float*)d_in[0];
  const float* rw = (const float*)d_in[1];
  const float* w1 = (const float*)d_in[2];
  const float* w2 = (const float*)d_in[3];
  float* out = (float*)d_out;
  char* ws = (char*)d_ws;

  size_t o = 0;
  auto alloc = [&](size_t b) { size_t r = o; o += (b + 255) & ~(size_t)255; return r; };
  __hip_bfloat16* xb    = (__hip_bfloat16*)(ws + alloc(2048UL*768*2));
  __hip_bfloat16* w1t   = (__hip_bfloat16*)(ws + alloc(16384UL*768*2));
  __hip_bfloat16* w2t   = (__hip_bfloat16*)(ws + alloc(768UL*16384*2));
  __hip_bfloat16* hprm  = (__hip_bfloat16*)(ws + alloc((size_t)PAD_SLOTS*256*2));
  __hip_bfloat16* yprm  = (__hip_bfloat16*)(ws + alloc((size_t)PAD_SLOTS*768*2));
  int*   sel_e   = (int*)  (ws + alloc(16384UL*4));
  float* sel_w   = (float*)(ws + alloc(16384UL*4));
  int*   slot_tk = (int*)  (ws + alloc(16384UL*4));
  int*   tokslot = (int*)  (ws + alloc((size_t)PAD_SLOTS*4));
  float* wgtslot = (float*)(ws + alloc((size_t)PAD_SLOTS*4));
  int*   counts  = (int*)  (ws + alloc(256));
  int*   cursor  = (int*)  (ws + alloc(256));
  float* psum    = (float*)(ws + alloc(256));
  float* scal    = (float*)(ws + alloc(256));
  int*   offsets = (int*)  (ws + alloc(256));
  int*   sch_e   = (int*)  (ws + alloc(640*4));
  int*   sch_r0  = (int*)  (ws + alloc(640*4));
  int*   ntiles  = (int*)  (ws + alloc(256));

  k_init<<<72, 256, 0, stream>>>(counts, cursor, psum, scal, wgtslot);
  k_cvt_x<<<1536, 256, 0, stream>>>(x, xb);
  k_transpose_cvt<<<dim3(512, 24), 256, 0, stream>>>(w1, w1t, 768, 16384);
  k_transpose_cvt<<<dim3(24, 512), 256, 0, stream>>>(w2, w2t, 16384, 768);
  k_router<<<512, 256, 0, stream>>>(x, rw, sel_e, sel_w, counts, psum, scal);
  k_schedule<<<1, 64, 0, stream>>>(counts, offsets, sch_e, sch_r0, ntiles);
  k_assign<<<64, 256, 0, stream>>>(sel_e, sel_w, offsets, cursor, tokslot, wgtslot, slot_tk);
  k_moe_gemm<1><<<576, 256, 0, stream>>>(xb, w1t, sch_e, sch_r0, ntiles, tokslot, wgtslot, (void*)hprm);
  k_moe_gemm<2><<<dim3(576, 3), 256, 0, stream>>>(hprm, w2t, sch_e, sch_r0, ntiles, tokslot, wgtslot, (void*)yprm);
  k_combine<<<2048, 256, 0, stream>>>(yprm, slot_tk, out);
  k_finalize<<<1, 64, 0, stream>>>(counts, psum, scal, out);
}

// Round 2
// 229.425 us; speedup vs baseline: 1.1392x; 1.1392x over previous
//
#include <hip/hip_runtime.h>
#include <hip/hip_bf16.h>

#define T_TOKENS 2048
#define D_EMBD 768
#define N_EXP 64
#define EW 256
#define TOPK 8
#define TW (N_EXP*EW)
#define PAD_SLOTS 18432   // 16384 + 64*31 rounded up
#define OUT_BASE (2048*768)

typedef __attribute__((ext_vector_type(8))) short bf16x8;
typedef __attribute__((ext_vector_type(4))) float f32x4;

typedef __attribute__((address_space(1))) void GAS;
typedef __attribute__((address_space(3))) void LAS;
#define GLOAD16(g, l) __builtin_amdgcn_global_load_lds((GAS*)(g), (LAS*)(l), 16, 0, 0)

// ---------------- init ----------------
__global__ void k_init(int* counts, int* cursor, float* psum, float* scal, float* wgt_slot) {
  int i = blockIdx.x*256 + threadIdx.x;
  if (i < N_EXP) { counts[i] = 0; cursor[i] = 0; psum[i] = 0.f; }
  if (i < 2) scal[i] = 0.f;
  if (i < PAD_SLOTS) wgt_slot[i] = 0.f;
}

// ---------------- x -> bf16 ----------------
__global__ void k_cvt_x(const float* __restrict__ x, __hip_bfloat16* __restrict__ xb) {
  int i = blockIdx.x*256 + threadIdx.x;   // 393216 threads, 4 elems each
  float4 v = reinterpret_cast<const float4*>(x)[i];
  union { __hip_bfloat16 b; unsigned short u; } c0, c1, c2, c3;
  c0.b = __float2bfloat16(v.x); c1.b = __float2bfloat16(v.y);
  c2.b = __float2bfloat16(v.z); c3.b = __float2bfloat16(v.w);
  ushort4 o; o.x = c0.u; o.y = c1.u; o.z = c2.u; o.w = c3.u;
  reinterpret_cast<ushort4*>(xb)[i] = o;
}

// ---------------- transpose + convert: src[R][C] f32 -> dst[C][R] bf16 ----------------
__global__ void k_transpose_cvt(const float* __restrict__ src, __hip_bfloat16* __restrict__ dst,
                                int R, int C) {
  __shared__ float tile[32][33];
  int bx = blockIdx.x*32, by = blockIdx.y*32;
  int tx = threadIdx.x & 31, ty = threadIdx.x >> 5;   // 32 x 8
  #pragma unroll
  for (int i = 0; i < 32; i += 8)
    tile[ty+i][tx] = src[(size_t)(by+ty+i)*C + bx+tx];
  __syncthreads();
  #pragma unroll
  for (int i = 0; i < 32; i += 8)
    dst[(size_t)(bx+ty+i)*R + by+tx] = __float2bfloat16(tile[tx][ty+i]);
}

// ---------------- router logits GEMM: lp[kc][t][e] partial sums ----------------
// grid (8 token-groups, 8 expert-groups, 3 k-chunks), 256 threads; thread = token.
__global__ __launch_bounds__(256) void k_logits(const float* __restrict__ x,
                                                const float* __restrict__ rw,
                                                float* __restrict__ lp) {
  __shared__ float rw_s[8][256];
  int tid = threadIdx.x;
  int tg = blockIdx.x, eg = blockIdx.y, kc = blockIdx.z;
  // stage rw chunk [8 experts][256 k] coalesced
  #pragma unroll
  for (int idx = 0; idx < 8; idx++) {
    int e = idx, kk = tid;
    rw_s[e][kk] = rw[(size_t)(eg*8 + e)*D_EMBD + kc*256 + kk];
  }
  __syncthreads();
  int tok = tg*256 + tid;
  const float4* x4 = reinterpret_cast<const float4*>(x + (size_t)tok*D_EMBD + kc*256);
  float acc[8];
  #pragma unroll
  for (int e = 0; e < 8; e++) acc[e] = 0.f;
  #pragma unroll 4
  for (int k4 = 0; k4 < 64; k4++) {
    float4 xv = x4[k4];
    #pragma unroll
    for (int e = 0; e < 8; e++) {
      acc[e] += xv.x*rw_s[e][k4*4+0] + xv.y*rw_s[e][k4*4+1]
              + xv.z*rw_s[e][k4*4+2] + xv.w*rw_s[e][k4*4+3];
    }
  }
  float* dst = lp + (size_t)kc*T_TOKENS*N_EXP + (size_t)tok*N_EXP + eg*8;
  float4 o0 = {acc[0], acc[1], acc[2], acc[3]};
  float4 o1 = {acc[4], acc[5], acc[6], acc[7]};
  reinterpret_cast<float4*>(dst)[0] = o0;
  reinterpret_cast<float4*>(dst)[1] = o1;
}

// ---------------- router part 2: sigmoid, top-8, losses (block-reduced atomics) ----------------
__global__ void k_router2(const float* __restrict__ lp,
                          int* __restrict__ sel_e, float* __restrict__ sel_w,
                          int* __restrict__ counts, float* __restrict__ psum,
                          float* __restrict__ scal) {
  __shared__ float psum_s[4][64];
  __shared__ int cnt_s[4][64];
  int tid = threadIdx.x, wv = tid >> 6, lane = tid & 63;
  psum_s[wv][lane] = 0.f; cnt_s[wv][lane] = 0;
  float zacc = 0.f, cacc = 0.f;
  int tbase = blockIdx.x*32 + wv*8;
  for (int it = 0; it < 8; it++) {
    int t = tbase + it;
    float logit = lp[(size_t)t*N_EXP + lane]
                + lp[(size_t)T_TOKENS*N_EXP + (size_t)t*N_EXP + lane]
                + lp[2*(size_t)T_TOKENS*N_EXP + (size_t)t*N_EXP + lane];
    float prob = 1.f/(1.f + expf(-logit));
    float mx = logit;
    for (int s = 32; s; s >>= 1) mx = fmaxf(mx, __shfl_xor(mx, s, 64));
    float sse = expf(logit - mx);
    for (int s = 32; s; s >>= 1) sse += __shfl_xor(sse, s, 64);
    float lse = mx + logf(sse);
    float ps = prob;
    for (int s = 32; s; s >>= 1) ps += __shfl_xor(ps, s, 64);
    zacc += lse*lse; cacc += ps;
    psum_s[wv][lane] += prob;
    // top-8 with jax tie-break (lower index wins on equality)
    float cur = prob;
    float selp = 0.f; int sele = 0;
    #pragma unroll
    for (int k = 0; k < TOPK; k++) {
      float bp = cur; int be = lane;
      for (int s = 32; s; s >>= 1) {
        float op = __shfl_xor(bp, s, 64);
        int oe = __shfl_xor(be, s, 64);
        if (op > bp || (op == bp && oe < be)) { bp = op; be = oe; }
      }
      if (lane == be) cur = -1.f;
      if (lane == k) { selp = bp; sele = be; }
    }
    cnt_s[wv][lane] += (cur < 0.f) ? 1 : 0;
    float wsum = (lane < TOPK) ? selp : 0.f;
    for (int s = 32; s; s >>= 1) wsum += __shfl_xor(wsum, s, 64);
    if (lane < TOPK) {
      sel_e[t*TOPK + lane] = sele;
      sel_w[t*TOPK + lane] = selp / (wsum + 1e-20f);
    }
  }
  if (lane == 0) { atomicAdd(&scal[0], zacc); atomicAdd(&scal[1], cacc); }
  __syncthreads();
  if (tid < 64) {
    float p = psum_s[0][tid] + psum_s[1][tid] + psum_s[2][tid] + psum_s[3][tid];
    int c = cnt_s[0][tid] + cnt_s[1][tid] + cnt_s[2][tid] + cnt_s[3][tid];
    atomicAdd(&psum[tid], p);
    atomicAdd(&counts[tid], c);
  }
}

// ---------------- schedule: padded offsets + tile list (trivial serial) ----------------
__global__ void k_schedule(const int* __restrict__ counts, int* __restrict__ offsets,
                           int* __restrict__ sched_e, int* __restrict__ sched_r0,
                           int* __restrict__ ntiles) {
  if (threadIdx.x == 0) {
    int off = 0, tt = 0;
    for (int e = 0; e < N_EXP; e++) {
      offsets[e] = off;
      int tiles = (counts[e] + 31) >> 5;
      for (int i = 0; i < tiles; i++) { sched_e[tt] = e; sched_r0[tt] = off + i*32; tt++; }
      off += tiles << 5;
    }
    ntiles[0] = tt;
  }
}

// ---------------- assign tokens to slots ----------------
__global__ void k_assign(const int* __restrict__ sel_e, const float* __restrict__ sel_w,
                         const int* __restrict__ offsets, int* __restrict__ cursor,
                         int* __restrict__ tok_slot, float* __restrict__ wgt_slot,
                         int* __restrict__ slot_tk) {
  int i = blockIdx.x*256 + threadIdx.x;   // 16384
  int e = sel_e[i];
  int pos = atomicAdd(&cursor[e], 1);
  int slot = offsets[e] + pos;
  tok_slot[slot] = i >> 3;
  wgt_slot[slot] = sel_w[i];
  slot_tk[i] = slot;
}

// ---------------- grouped GEMM (MODE 1: x@W1 -> relu^2*gate -> h ; MODE 2: h@W2 -> y) ----------------
// tile: 32 rows x 256 cols, BK=64, 4 waves, mfma 16x16x32 bf16.
// LDS chunk swizzle: chunk kc at (row) stores global chunk (kc ^ (row&7)); same XOR on read.
template<int MODE>
__global__ __launch_bounds__(256) void k_moe_gemm(
    const __hip_bfloat16* __restrict__ Ab, const __hip_bfloat16* __restrict__ Bt,
    const int* __restrict__ sched_e, const int* __restrict__ sched_r0,
    const int* __restrict__ ntiles, const int* __restrict__ tok_slot,
    const float* __restrict__ wgt_slot, void* __restrict__ outp) {
  int tile = blockIdx.x;
  if (tile >= ntiles[0]) return;
  int e = sched_e[tile], r0 = sched_r0[tile];
  int nch = (MODE == 2) ? blockIdx.y : 0;
  constexpr int KT = (MODE == 1) ? 768 : 256;
  __shared__ __hip_bfloat16 As[32*64];
  __shared__ __hip_bfloat16 Bs[256*64];
  int tid = threadIdx.x;
  int arow = tid >> 3, akc = tid & 7;
  size_t a_base;
  if (MODE == 1) {
    int tok = tok_slot[r0 + arow];
    tok = min(max(tok, 0), T_TOKENS - 1);   // padded slots clamp; gate=0 kills them
    a_base = (size_t)tok * D_EMBD;
  } else {
    a_base = (size_t)(r0 + arow) * EW;
  }
  int a_off = ((akc ^ (arow & 7)) << 3);
  size_t b_base; int b_str;
  if (MODE == 1) { b_str = D_EMBD; b_base = (size_t)(e*EW) * D_EMBD; }
  else { b_str = TW; b_base = (size_t)(nch*EW) * TW + (size_t)e*EW; }

  f32x4 acc[2][4];
  f32x4 z = {0.f, 0.f, 0.f, 0.f};
  #pragma unroll
  for (int m = 0; m < 2; m++)
    #pragma unroll
    for (int n = 0; n < 4; n++) acc[m][n] = z;

  int wv = tid >> 6, lane = tid & 63;
  int l15 = lane & 15, l4 = lane >> 4;
  int brow_ = tid >> 3, bkc = tid & 7;

  for (int k0 = 0; k0 < KT; k0 += 64) {
    __syncthreads();
    GLOAD16(Ab + a_base + k0 + a_off, As + tid*8);
    #pragma unroll
    for (int i = 0; i < 8; i++) {
      int br = i*32 + brow_;
      int boff = ((bkc ^ (br & 7)) << 3);
      GLOAD16(Bt + b_base + (size_t)br*b_str + k0 + boff, Bs + (i*256 + tid)*8);
    }
    asm volatile("s_waitcnt vmcnt(0)" ::: "memory");
    __syncthreads();
    const bf16x8* A8 = reinterpret_cast<const bf16x8*>(As);
    const bf16x8* B8 = reinterpret_cast<const bf16x8*>(Bs);
    bf16x8 af[2][2], bq[4][2];
    #pragma unroll
    for (int m = 0; m < 2; m++) {
      int ra = m*16 + l15;
      #pragma unroll
      for (int kk = 0; kk < 2; kk++)
        af[m][kk] = A8[ra*8 + ((kk*4 + l4) ^ (ra & 7))];
    }
    #pragma unroll
    for (int n = 0; n < 4; n++) {
      int rb = wv*64 + n*16 + l15;
      #pragma unroll
      for (int kk = 0; kk < 2; kk++)
        bq[n][kk] = B8[rb*8 + ((kk*4 + l4) ^ (rb & 7))];
    }
    #pragma unroll
    for (int kk = 0; kk < 2; kk++)
      #pragma unroll
      for (int m = 0; m < 2; m++)
        #pragma unroll
        for (int n = 0; n < 4; n++)
          acc[m][n] = __builtin_amdgcn_mfma_f32_16x16x32_bf16(af[m][kk], bq[n][kk], acc[m][n], 0, 0, 0);
  }

  if (MODE == 1) {
    __hip_bfloat16* h = (__hip_bfloat16*)outp;
    #pragma unroll
    for (int m = 0; m < 2; m++)
      #pragma unroll
      for (int j = 0; j < 4; j++) {
        int r = r0 + m*16 + l4*4 + j;
        float wg = wgt_slot[r];
        #pragma unroll
        for (int n = 0; n < 4; n++) {
          int col = wv*64 + n*16 + l15;
          float v = fmaxf(acc[m][n][j], 0.f);
          h[(size_t)r*EW + col] = __float2bfloat16(v*v*wg);
        }
      }
  } else {
    __hip_bfloat16* y = (__hip_bfloat16*)outp;
    #pragma unroll
    for (int m = 0; m < 2; m++)
      #pragma unroll
      for (int j = 0; j < 4; j++) {
        int r = r0 + m*16 + l4*4 + j;
        #pragma unroll
        for (int n = 0; n < 4; n++) {
          int col = nch*EW + wv*64 + n*16 + l15;
          y[(size_t)r*D_EMBD + col] = __float2bfloat16(acc[m][n][j]);
        }
      }
  }
}

// ---------------- combine 8 expert rows per token ----------------
__global__ void k_combine(const __hip_bfloat16* __restrict__ y, const int* __restrict__ slot_tk,
                          float* __restrict__ out) {
  __shared__ int s[TOPK];
  int t = blockIdx.x, tid = threadIdx.x;
  if (tid < TOPK) s[tid] = slot_tk[t*TOPK + tid];
  __syncthreads();
  for (int c = tid; c < D_EMBD; c += 256) {
    float a = 0.f;
    #pragma unroll
    for (int k = 0; k < TOPK; k++)
      a += __bfloat162float(y[(size_t)s[k]*D_EMBD + c]);
    out[(size_t)t*D_EMBD + c] = a;
  }
}

// ---------------- aux losses + f_i ----------------
__global__ void k_finalize(const int* __restrict__ counts, const float* __restrict__ psum,
                           const float* __restrict__ scal, float* __restrict__ out) {
  __shared__ float part[N_EXP];
  int e = threadIdx.x;
  float f = (float)counts[e] / 16384.f;
  float p = psum[e] / 2048.f;
  part[e] = f * p;
  out[OUT_BASE + 3 + e] = f;
  __syncthreads();
  if (e == 0) {
    float s = 0.f;
    for (int i = 0; i < N_EXP; i++) s += part[i];
    out[OUT_BASE + 0] = scal[0] / 2048.f;      // router_z_loss
    out[OUT_BASE + 1] = 64.f * s;              // load_balance_loss
    out[OUT_BASE + 2] = scal[1] / 2048.f;      // compute_loss
  }
}

extern "C" void kernel_launch(void* const* d_in, const int* in_sizes, int n_in,
                              void* d_out, int out_size, void* d_ws, size_t ws_size,
                              hipStream_t stream) {
  const float* x  = (const float*)d_in[0];
  const float* rw = (const float*)d_in[1];
  const float* w1 = (const float*)d_in[2];
  const float* w2 = (const float*)d_in[3];
  float* out = (float*)d_out;
  char* ws = (char*)d_ws;

  size_t o = 0;
  auto alloc = [&](size_t b) { size_t r = o; o += (b + 255) & ~(size_t)255; return r; };
  __hip_bfloat16* xb    = (__hip_bfloat16*)(ws + alloc(2048UL*768*2));
  __hip_bfloat16* w1t   = (__hip_bfloat16*)(ws + alloc(16384UL*768*2));
  __hip_bfloat16* w2t   = (__hip_bfloat16*)(ws + alloc(768UL*16384*2));
  __hip_bfloat16* hprm  = (__hip_bfloat16*)(ws + alloc((size_t)PAD_SLOTS*256*2));
  __hip_bfloat16* yprm  = (__hip_bfloat16*)(ws + alloc((size_t)PAD_SLOTS*768*2));
  float* lp      = (float*)(ws + alloc(3UL*2048*64*4));
  int*   sel_e   = (int*)  (ws + alloc(16384UL*4));
  float* sel_w   = (float*)(ws + alloc(16384UL*4));
  int*   slot_tk = (int*)  (ws + alloc(16384UL*4));
  int*   tokslot = (int*)  (ws + alloc((size_t)PAD_SLOTS*4));
  float* wgtslot = (float*)(ws + alloc((size_t)PAD_SLOTS*4));
  int*   counts  = (int*)  (ws + alloc(256));
  int*   cursor  = (int*)  (ws + alloc(256));
  float* psum    = (float*)(ws + alloc(256));
  float* scal    = (float*)(ws + alloc(256));
  int*   offsets = (int*)  (ws + alloc(256));
  int*   sch_e   = (int*)  (ws + alloc(640*4));
  int*   sch_r0  = (int*)  (ws + alloc(640*4));
  int*   ntiles  = (int*)  (ws + alloc(256));

  k_init<<<72, 256, 0, stream>>>(counts, cursor, psum, scal, wgtslot);
  k_cvt_x<<<1536, 256, 0, stream>>>(x, xb);
  k_transpose_cvt<<<dim3(512, 24), 256, 0, stream>>>(w1, w1t, 768, 16384);
  k_transpose_cvt<<<dim3(24, 512), 256, 0, stream>>>(w2, w2t, 16384, 768);
  k_logits<<<dim3(8, 8, 3), 256, 0, stream>>>(x, rw, lp);
  k_router2<<<64, 256, 0, stream>>>(lp, sel_e, sel_w, counts, psum, scal);
  k_schedule<<<1, 64, 0, stream>>>(counts, offsets, sch_e, sch_r0, ntiles);
  k_assign<<<64, 256, 0, stream>>>(sel_e, sel_w, offsets, cursor, tokslot, wgtslot, slot_tk);
  k_moe_gemm<1><<<576, 256, 0, stream>>>(xb, w1t, sch_e, sch_r0, ntiles, tokslot, wgtslot, (void*)hprm);
  k_moe_gemm<2><<<dim3(576, 3), 256, 0, stream>>>(hprm, w2t, sch_e, sch_r0, ntiles, tokslot, wgtslot, (void*)yprm);
  k_combine<<<2048, 256, 0, stream>>>(yprm, slot_tk, out);
  k_finalize<<<1, 64, 0, stream>>>(counts, psum, scal, out);
}

// Round 3
// 204.619 us; speedup vs baseline: 1.2773x; 1.1212x over previous
//
#include <hip/hip_runtime.h>
#include <hip/hip_bf16.h>

#define T_TOKENS 2048
#define D_EMBD 768
#define N_EXP 64
#define EW 256
#define TOPK 8
#define TW (N_EXP*EW)
#define PAD_SLOTS 18432   // 16384 + 64*31 rounded up
#define OUT_BASE (2048*768)

typedef __attribute__((ext_vector_type(8))) short bf16x8;
typedef __attribute__((ext_vector_type(4))) float f32x4;

typedef __attribute__((address_space(1))) void GAS;
typedef __attribute__((address_space(3))) void LAS;
#define GLOAD16(g, l) __builtin_amdgcn_global_load_lds((GAS*)(g), (LAS*)(l), 16, 0, 0)

// ---------------- init ----------------
__global__ void k_init(int* counts, int* cursor, float* psum, float* scal, float* wgt_slot) {
  int i = blockIdx.x*256 + threadIdx.x;
  if (i < N_EXP) { counts[i] = 0; cursor[i] = 0; psum[i] = 0.f; }
  if (i < 2) scal[i] = 0.f;
  if (i < PAD_SLOTS) wgt_slot[i] = 0.f;
}

// ---------------- x -> bf16 ----------------
__global__ void k_cvt_x(const float* __restrict__ x, __hip_bfloat16* __restrict__ xb) {
  int i = blockIdx.x*256 + threadIdx.x;   // 393216 threads, 4 elems each
  float4 v = reinterpret_cast<const float4*>(x)[i];
  union { __hip_bfloat16 b; unsigned short u; } c0, c1, c2, c3;
  c0.b = __float2bfloat16(v.x); c1.b = __float2bfloat16(v.y);
  c2.b = __float2bfloat16(v.z); c3.b = __float2bfloat16(v.w);
  ushort4 o; o.x = c0.u; o.y = c1.u; o.z = c2.u; o.w = c3.u;
  reinterpret_cast<ushort4*>(xb)[i] = o;
}

// ---------------- transpose + convert: src[R][C] f32 -> dst[C][R] bf16 ----------------
__global__ void k_transpose_cvt(const float* __restrict__ src, __hip_bfloat16* __restrict__ dst,
                                int R, int C) {
  __shared__ float tile[32][33];
  int bx = blockIdx.x*32, by = blockIdx.y*32;
  int tx = threadIdx.x & 31, ty = threadIdx.x >> 5;   // 32 x 8
  #pragma unroll
  for (int i = 0; i < 32; i += 8)
    tile[ty+i][tx] = src[(size_t)(by+ty+i)*C + bx+tx];
  __syncthreads();
  #pragma unroll
  for (int i = 0; i < 32; i += 8)
    dst[(size_t)(bx+ty+i)*R + by+tx] = __float2bfloat16(tile[tx][ty+i]);
}

// ---------------- router logits GEMM: lp[kc][t][e] partial sums ----------------
__global__ __launch_bounds__(256) void k_logits(const float* __restrict__ x,
                                                const float* __restrict__ rw,
                                                float* __restrict__ lp) {
  __shared__ float rw_s[8][256];
  int tid = threadIdx.x;
  int tg = blockIdx.x, eg = blockIdx.y, kc = blockIdx.z;
  #pragma unroll
  for (int idx = 0; idx < 8; idx++) {
    rw_s[idx][tid] = rw[(size_t)(eg*8 + idx)*D_EMBD + kc*256 + tid];
  }
  __syncthreads();
  int tok = tg*256 + tid;
  const float4* x4 = reinterpret_cast<const float4*>(x + (size_t)tok*D_EMBD + kc*256);
  float acc[8];
  #pragma unroll
  for (int e = 0; e < 8; e++) acc[e] = 0.f;
  #pragma unroll 4
  for (int k4 = 0; k4 < 64; k4++) {
    float4 xv = x4[k4];
    #pragma unroll
    for (int e = 0; e < 8; e++) {
      acc[e] += xv.x*rw_s[e][k4*4+0] + xv.y*rw_s[e][k4*4+1]
              + xv.z*rw_s[e][k4*4+2] + xv.w*rw_s[e][k4*4+3];
    }
  }
  float* dst = lp + (size_t)kc*T_TOKENS*N_EXP + (size_t)tok*N_EXP + eg*8;
  float4 o0 = {acc[0], acc[1], acc[2], acc[3]};
  float4 o1 = {acc[4], acc[5], acc[6], acc[7]};
  reinterpret_cast<float4*>(dst)[0] = o0;
  reinterpret_cast<float4*>(dst)[1] = o1;
}

// ---------------- router part 2: sigmoid, parallel-rank top-8, losses ----------------
// wave = token (2 tokens/wave), rank via 64 independent broadcasts.
__global__ __launch_bounds__(256) void k_router2(const float* __restrict__ lp,
                          int* __restrict__ sel_e, float* __restrict__ sel_w,
                          int* __restrict__ counts, float* __restrict__ psum,
                          float* __restrict__ scal) {
  __shared__ float psum_s[4][64];
  __shared__ int cnt_s[4][64];
  int tid = threadIdx.x, wv = tid >> 6, lane = tid & 63;
  float pacc = 0.f, zacc = 0.f;
  int cacc = 0;
  int tbase = blockIdx.x*8 + wv*2;
  #pragma unroll
  for (int it = 0; it < 2; it++) {
    int t = tbase + it;
    float logit = lp[(size_t)t*N_EXP + lane]
                + lp[(size_t)T_TOKENS*N_EXP + (size_t)t*N_EXP + lane]
                + lp[2*(size_t)T_TOKENS*N_EXP + (size_t)t*N_EXP + lane];
    float prob = 1.f/(1.f + expf(-logit));
    pacc += prob;
    // logsumexp (stable)
    float mx = logit;
    for (int s = 32; s; s >>= 1) mx = fmaxf(mx, __shfl_xor(mx, s, 64));
    float sse = expf(logit - mx);
    for (int s = 32; s; s >>= 1) sse += __shfl_xor(sse, s, 64);
    float lse = mx + logf(sse);
    zacc += lse*lse;
    // parallel rank: descending order, ties -> lower index (matches jax top_k)
    int rank = 0;
    #pragma unroll
    for (int j = 0; j < 64; j++) {
      float pj = __shfl(prob, j, 64);
      rank += (pj > prob || (pj == prob && j < lane)) ? 1 : 0;
    }
    bool sel = rank < TOPK;
    float sp = sel ? prob : 0.f;
    for (int s = 32; s; s >>= 1) sp += __shfl_xor(sp, s, 64);
    if (sel) {
      sel_e[t*TOPK + rank] = lane;
      sel_w[t*TOPK + rank] = prob / (sp + 1e-20f);
      cacc++;
    }
  }
  psum_s[wv][lane] = pacc;
  cnt_s[wv][lane] = cacc;
  if (lane == 0) atomicAdd(&scal[0], zacc);
  __syncthreads();
  if (tid < 64) {
    float p = psum_s[0][tid] + psum_s[1][tid] + psum_s[2][tid] + psum_s[3][tid];
    int c = cnt_s[0][tid] + cnt_s[1][tid] + cnt_s[2][tid] + cnt_s[3][tid];
    atomicAdd(&psum[tid], p);
    atomicAdd(&counts[tid], c);
  }
}

// ---------------- schedule: padded offsets + tile list (trivial serial) ----------------
__global__ void k_schedule(const int* __restrict__ counts, int* __restrict__ offsets,
                           int* __restrict__ sched_e, int* __restrict__ sched_r0,
                           int* __restrict__ ntiles) {
  if (threadIdx.x == 0) {
    int off = 0, tt = 0;
    for (int e = 0; e < N_EXP; e++) {
      offsets[e] = off;
      int tiles = (counts[e] + 31) >> 5;
      for (int i = 0; i < tiles; i++) { sched_e[tt] = e; sched_r0[tt] = off + i*32; tt++; }
      off += tiles << 5;
    }
    ntiles[0] = tt;
  }
}

// ---------------- assign tokens to slots ----------------
__global__ void k_assign(const int* __restrict__ sel_e, const float* __restrict__ sel_w,
                         const int* __restrict__ offsets, int* __restrict__ cursor,
                         int* __restrict__ tok_slot, float* __restrict__ wgt_slot,
                         int* __restrict__ slot_tk) {
  int i = blockIdx.x*256 + threadIdx.x;   // 16384
  int e = sel_e[i];
  int pos = atomicAdd(&cursor[e], 1);
  int slot = offsets[e] + pos;
  tok_slot[slot] = i >> 3;
  wgt_slot[slot] = sel_w[i];
  slot_tk[i] = slot;
}

// ---------------- grouped GEMM (MODE 1: x@W1 -> relu^2*gate -> h ; MODE 2: h@W2 -> y) ----------------
template<int MODE>
__global__ __launch_bounds__(256) void k_moe_gemm(
    const __hip_bfloat16* __restrict__ Ab, const __hip_bfloat16* __restrict__ Bt,
    const int* __restrict__ sched_e, const int* __restrict__ sched_r0,
    const int* __restrict__ ntiles, const int* __restrict__ tok_slot,
    const float* __restrict__ wgt_slot, void* __restrict__ outp) {
  int tile = blockIdx.x;
  if (tile >= ntiles[0]) return;
  int e = sched_e[tile], r0 = sched_r0[tile];
  int nch = (MODE == 2) ? blockIdx.y : 0;
  constexpr int KT = (MODE == 1) ? 768 : 256;
  __shared__ __hip_bfloat16 As[32*64];
  __shared__ __hip_bfloat16 Bs[256*64];
  int tid = threadIdx.x;
  int arow = tid >> 3, akc = tid & 7;
  size_t a_base;
  if (MODE == 1) {
    int tok = tok_slot[r0 + arow];
    tok = min(max(tok, 0), T_TOKENS - 1);   // padded slots clamp; gate=0 kills them
    a_base = (size_t)tok * D_EMBD;
  } else {
    a_base = (size_t)(r0 + arow) * EW;
  }
  int a_off = ((akc ^ (arow & 7)) << 3);
  size_t b_base; int b_str;
  if (MODE == 1) { b_str = D_EMBD; b_base = (size_t)(e*EW) * D_EMBD; }
  else { b_str = TW; b_base = (size_t)(nch*EW) * TW + (size_t)e*EW; }

  f32x4 acc[2][4];
  f32x4 z = {0.f, 0.f, 0.f, 0.f};
  #pragma unroll
  for (int m = 0; m < 2; m++)
    #pragma unroll
    for (int n = 0; n < 4; n++) acc[m][n] = z;

  int wv = tid >> 6, lane = tid & 63;
  int l15 = lane & 15, l4 = lane >> 4;
  int brow_ = tid >> 3, bkc = tid & 7;

  for (int k0 = 0; k0 < KT; k0 += 64) {
    __syncthreads();
    GLOAD16(Ab + a_base + k0 + a_off, As + tid*8);
    #pragma unroll
    for (int i = 0; i < 8; i++) {
      int br = i*32 + brow_;
      int boff = ((bkc ^ (br & 7)) << 3);
      GLOAD16(Bt + b_base + (size_t)br*b_str + k0 + boff, Bs + (i*256 + tid)*8);
    }
    asm volatile("s_waitcnt vmcnt(0)" ::: "memory");
    __syncthreads();
    const bf16x8* A8 = reinterpret_cast<const bf16x8*>(As);
    const bf16x8* B8 = reinterpret_cast<const bf16x8*>(Bs);
    bf16x8 af[2][2], bq[4][2];
    #pragma unroll
    for (int m = 0; m < 2; m++) {
      int ra = m*16 + l15;
      #pragma unroll
      for (int kk = 0; kk < 2; kk++)
        af[m][kk] = A8[ra*8 + ((kk*4 + l4) ^ (ra & 7))];
    }
    #pragma unroll
    for (int n = 0; n < 4; n++) {
      int rb = wv*64 + n*16 + l15;
      #pragma unroll
      for (int kk = 0; kk < 2; kk++)
        bq[n][kk] = B8[rb*8 + ((kk*4 + l4) ^ (rb & 7))];
    }
    #pragma unroll
    for (int kk = 0; kk < 2; kk++)
      #pragma unroll
      for (int m = 0; m < 2; m++)
        #pragma unroll
        for (int n = 0; n < 4; n++)
          acc[m][n] = __builtin_amdgcn_mfma_f32_16x16x32_bf16(af[m][kk], bq[n][kk], acc[m][n], 0, 0, 0);
  }

  if (MODE == 1) {
    __hip_bfloat16* h = (__hip_bfloat16*)outp;
    #pragma unroll
    for (int m = 0; m < 2; m++)
      #pragma unroll
      for (int j = 0; j < 4; j++) {
        int r = r0 + m*16 + l4*4 + j;
        float wg = wgt_slot[r];
        #pragma unroll
        for (int n = 0; n < 4; n++) {
          int col = wv*64 + n*16 + l15;
          float v = fmaxf(acc[m][n][j], 0.f);
          h[(size_t)r*EW + col] = __float2bfloat16(v*v*wg);
        }
      }
  } else {
    __hip_bfloat16* y = (__hip_bfloat16*)outp;
    #pragma unroll
    for (int m = 0; m < 2; m++)
      #pragma unroll
      for (int j = 0; j < 4; j++) {
        int r = r0 + m*16 + l4*4 + j;
        #pragma unroll
        for (int n = 0; n < 4; n++) {
          int col = nch*EW + wv*64 + n*16 + l15;
          y[(size_t)r*D_EMBD + col] = __float2bfloat16(acc[m][n][j]);
        }
      }
  }
}

// ---------------- combine 8 expert rows per token ----------------
__global__ void k_combine(const __hip_bfloat16* __restrict__ y, const int* __restrict__ slot_tk,
                          float* __restrict__ out) {
  __shared__ int s[TOPK];
  int t = blockIdx.x, tid = threadIdx.x;
  if (tid < TOPK) s[tid] = slot_tk[t*TOPK + tid];
  __syncthreads();
  for (int c = tid; c < D_EMBD; c += 256) {
    float a = 0.f;
    #pragma unroll
    for (int k = 0; k < TOPK; k++)
      a += __bfloat162float(y[(size_t)s[k]*D_EMBD + c]);
    out[(size_t)t*D_EMBD + c] = a;
  }
}

// ---------------- aux losses + f_i ----------------
__global__ void k_finalize(const int* __restrict__ counts, const float* __restrict__ psum,
                           const float* __restrict__ scal, float* __restrict__ out) {
  __shared__ float part[N_EXP], ptot[N_EXP];
  int e = threadIdx.x;
  float f = (float)counts[e] / 16384.f;
  float p = psum[e] / 2048.f;
  part[e] = f * p;
  ptot[e] = p;
  out[OUT_BASE + 3 + e] = f;
  __syncthreads();
  if (e == 0) {
    float s = 0.f, q = 0.f;
    for (int i = 0; i < N_EXP; i++) { s += part[i]; q += ptot[i]; }
    out[OUT_BASE + 0] = scal[0] / 2048.f;      // router_z_loss
    out[OUT_BASE + 1] = 64.f * s;              // load_balance_loss
    out[OUT_BASE + 2] = q;                     // compute_loss = sum_e mean_t prob
  }
}

extern "C" void kernel_launch(void* const* d_in, const int* in_sizes, int n_in,
                              void* d_out, int out_size, void* d_ws, size_t ws_size,
                              hipStream_t stream) {
  const float* x  = (const float*)d_in[0];
  const float* rw = (const float*)d_in[1];
  const float* w1 = (const float*)d_in[2];
  const float* w2 = (const float*)d_in[3];
  float* out = (float*)d_out;
  char* ws = (char*)d_ws;

  size_t o = 0;
  auto alloc = [&](size_t b) { size_t r = o; o += (b + 255) & ~(size_t)255; return r; };
  __hip_bfloat16* xb    = (__hip_bfloat16*)(ws + alloc(2048UL*768*2));
  __hip_bfloat16* w1t   = (__hip_bfloat16*)(ws + alloc(16384UL*768*2));
  __hip_bfloat16* w2t   = (__hip_bfloat16*)(ws + alloc(768UL*16384*2));
  __hip_bfloat16* hprm  = (__hip_bfloat16*)(ws + alloc((size_t)PAD_SLOTS*256*2));
  __hip_bfloat16* yprm  = (__hip_bfloat16*)(ws + alloc((size_t)PAD_SLOTS*768*2));
  float* lp      = (float*)(ws + alloc(3UL*2048*64*4));
  int*   sel_e   = (int*)  (ws + alloc(16384UL*4));
  float* sel_w   = (float*)(ws + alloc(16384UL*4));
  int*   slot_tk = (int*)  (ws + alloc(16384UL*4));
  int*   tokslot = (int*)  (ws + alloc((size_t)PAD_SLOTS*4));
  float* wgtslot = (float*)(ws + alloc((size_t)PAD_SLOTS*4));
  int*   counts  = (int*)  (ws + alloc(256));
  int*   cursor  = (int*)  (ws + alloc(256));
  float* psum    = (float*)(ws + alloc(256));
  float* scal    = (float*)(ws + alloc(256));
  int*   offsets = (int*)  (ws + alloc(256));
  int*   sch_e   = (int*)  (ws + alloc(640*4));
  int*   sch_r0  = (int*)  (ws + alloc(640*4));
  int*   ntiles  = (int*)  (ws + alloc(256));

  k_init<<<72, 256, 0, stream>>>(counts, cursor, psum, scal, wgtslot);
  k_cvt_x<<<1536, 256, 0, stream>>>(x, xb);
  k_transpose_cvt<<<dim3(512, 24), 256, 0, stream>>>(w1, w1t, 768, 16384);
  k_transpose_cvt<<<dim3(24, 512), 256, 0, stream>>>(w2, w2t, 16384, 768);
  k_logits<<<dim3(8, 8, 3), 256, 0, stream>>>(x, rw, lp);
  k_router2<<<256, 256, 0, stream>>>(lp, sel_e, sel_w, counts, psum, scal);
  k_schedule<<<1, 64, 0, stream>>>(counts, offsets, sch_e, sch_r0, ntiles);
  k_assign<<<64, 256, 0, stream>>>(sel_e, sel_w, offsets, cursor, tokslot, wgtslot, slot_tk);
  k_moe_gemm<1><<<576, 256, 0, stream>>>(xb, w1t, sch_e, sch_r0, ntiles, tokslot, wgtslot, (void*)hprm);
  k_moe_gemm<2><<<dim3(576, 3), 256, 0, stream>>>(hprm, w2t, sch_e, sch_r0, ntiles, tokslot, wgtslot, (void*)yprm);
  k_combine<<<2048, 256, 0, stream>>>(yprm, slot_tk, out);
  k_finalize<<<1, 64, 0, stream>>>(counts, psum, scal, out);
}